// Round 2
// baseline (60.948 us; speedup 1.0000x reference)
//
#include <hip/hip_runtime.h>

// out[d][c][h][w] = (h < d) ? left[c][h][w] - right[c][h + 128 - d][w] : 0
// N=1, C=16, H=128, W=256, D=128 (disps -128..-1, shift = 128 - d)
// Output: (1, 128, 16, 128, 256) fp32 = 256 MiB. Pure streaming write;
// inputs are 2 x 2 MiB (L2-resident). Roofline = write BW (~7 TB/s fill rate).

typedef float f32x4 __attribute__((ext_vector_type(4)));

__global__ __launch_bounds__(256) void CostDifference_kernel(
    const f32x4* __restrict__ left,
    const f32x4* __restrict__ right,
    f32x4* __restrict__ out) {
    // total float4 elements: 128 (d) * 16 (c) * 128 (h) * 64 (w4) = 2^24
    // 8192 blocks * 256 threads = 2^21 threads, 8 unrolled iterations each.
    constexpr int STRIDE = 8192 * 256;           // 2^21
    const int tid = blockIdx.x * 256 + threadIdx.x;

    // Lower 17 bits (w4,h,c) are iteration-invariant: STRIDE only bumps d by 16.
    const int w4 = tid & 63;
    const int h  = (tid >> 6) & 127;
    const int c  = (tid >> 13) & 15;
    const int d0 = tid >> 17;                    // 0..15

    const f32x4 l = left[(c * 128 + h) * 64 + w4];   // loop-invariant, 1 load
    const int rbase = c * 128 * 64 + w4;

#pragma unroll
    for (int it = 0; it < 8; ++it) {
        const int d  = d0 + it * 16;
        // valid iff h < d; clamp read index so the load is always in-bounds,
        // then predicate the result (no control flow -> stores batch up).
        const int hs = min(h + 128 - d, 127);
        const f32x4 r = right[rbase + hs * 64];
        const bool m = (h < d);
        f32x4 o;
        o.x = m ? (l.x - r.x) : 0.0f;
        o.y = m ? (l.y - r.y) : 0.0f;
        o.z = m ? (l.z - r.z) : 0.0f;
        o.w = m ? (l.w - r.w) : 0.0f;
        __builtin_nontemporal_store(o, &out[tid + it * STRIDE]);
    }
}

extern "C" void kernel_launch(void* const* d_in, const int* in_sizes, int n_in,
                              void* d_out, int out_size, void* d_ws, size_t ws_size,
                              hipStream_t stream) {
    const f32x4* left  = (const f32x4*)d_in[0];
    const f32x4* right = (const f32x4*)d_in[1];
    f32x4* out = (f32x4*)d_out;

    CostDifference_kernel<<<8192, 256, 0, stream>>>(left, right, out);
}

// Round 3
// 45.634 us; speedup vs baseline: 1.3356x; 1.3356x over previous
//
#include <hip/hip_runtime.h>

// out[d][c][h][w] = (h < d) ? left[c][h][w] - right[c][h + 128 - d][w] : 0
// N=1, C=16, H=128, W=256, D=128. Output (1,128,16,128,256) fp32 = 256 MiB.
//
// Bijection: data row (d,c,h) <-> input-row pair (h, hs=h+128-d) with h < hs.
// A wave caching 8 left rows + 8 right rows (1 row = 256 fp32 = one wave-wide
// float4) emits 64 output rows from 16 loads -> 4x read amortization.
// Zero region (h >= d) is contiguous per (d,c) slice -> pure-fill waves.
//
// Wave plan (3200 waves = 800 blocks x 4):
//   [0,1920)    full tiles: c=wave&15, p=wave>>4 -> (i,j), i<j  (64 rows each)
//   [1920,2176) diagonal tiles i==j: pairs a<b (28 rows each)
//   [2176,3200) zero waves: slices (d,c) and (127-d,c)  (129 rows each)

typedef float f32x4 __attribute__((ext_vector_type(4)));

__global__ __launch_bounds__(256) void CostDifference_kernel(
    const f32x4* __restrict__ left,
    const f32x4* __restrict__ right,
    f32x4* __restrict__ out)
{
    const int wave = (blockIdx.x << 2) | (threadIdx.x >> 6);
    const int lane = threadIdx.x & 63;

    if (wave < 1920) {
        // ---- full 8x8 row-pair tile, i < j: all 64 pairs valid ----
        const int c = wave & 15;
        int p = wave >> 4;                       // 0..119
        int i = 0;
        while (p >= 15 - i) { p -= 15 - i; ++i; }   // wave-uniform decode
        const int j = i + 1 + p;

        const int i8 = i << 3, j8 = j << 3;
        f32x4 L[8], R[8];
#pragma unroll
        for (int a = 0; a < 8; ++a) L[a] = left [(c * 128 + i8 + a) * 64 + lane];
#pragma unroll
        for (int b = 0; b < 8; ++b) R[b] = right[(c * 128 + j8 + b) * 64 + lane];

        // d = 128 + (i8+a) - (j8+b);  row = d*2048 + c*128 + (i8+a)
        const int base = (128 + i8 - j8) * 2048 + c * 128 + i8;
#pragma unroll
        for (int a = 0; a < 8; ++a) {
#pragma unroll
            for (int b = 0; b < 8; ++b) {
                const int row = base + a * 2049 - b * 2048;
                f32x4 o;
                o.x = L[a].x - R[b].x;
                o.y = L[a].y - R[b].y;
                o.z = L[a].z - R[b].z;
                o.w = L[a].w - R[b].w;
                out[row * 64 + lane] = o;
            }
        }
    } else if (wave < 2176) {
        // ---- diagonal tile i == j: pairs a < b (28 rows) ----
        const int t = wave - 1920;
        const int c = t & 15;
        const int i8 = (t >> 4) << 3;
        f32x4 L[8], R[8];
#pragma unroll
        for (int a = 0; a < 8; ++a) L[a] = left [(c * 128 + i8 + a) * 64 + lane];
#pragma unroll
        for (int b = 0; b < 8; ++b) R[b] = right[(c * 128 + i8 + b) * 64 + lane];

        const int base = 128 * 2048 + c * 128 + i8;   // i8 - j8 == 0
#pragma unroll
        for (int a = 0; a < 8; ++a) {
#pragma unroll
            for (int b = 0; b < 8; ++b) {
                if (a < b) {
                    const int row = base + a * 2049 - b * 2048;
                    f32x4 o;
                    o.x = L[a].x - R[b].x;
                    o.y = L[a].y - R[b].y;
                    o.z = L[a].z - R[b].z;
                    o.w = L[a].w - R[b].w;
                    out[row * 64 + lane] = o;
                }
            }
        }
    } else {
        // ---- zero waves: slices (d,c) and (127-d,c), rows h in [d,128) ----
        const int zw = wave - 2176;              // 0..1023
        const int c = zw & 15;
        const int d  = zw >> 4;                  // 0..63
        const int d2 = 127 - d;                  // 64..127
        const f32x4 zero = {0.f, 0.f, 0.f, 0.f};

        int rb = (d * 2048 + c * 128 + d) * 64 + lane;
        const int n1 = 128 - d;
#pragma unroll 4
        for (int k = 0; k < n1; ++k) out[rb + k * 64] = zero;

        rb = (d2 * 2048 + c * 128 + d2) * 64 + lane;
        const int n2 = 128 - d2;
#pragma unroll 4
        for (int k = 0; k < n2; ++k) out[rb + k * 64] = zero;
    }
}

extern "C" void kernel_launch(void* const* d_in, const int* in_sizes, int n_in,
                              void* d_out, int out_size, void* d_ws, size_t ws_size,
                              hipStream_t stream) {
    const f32x4* left  = (const f32x4*)d_in[0];
    const f32x4* right = (const f32x4*)d_in[1];
    f32x4* out = (f32x4*)d_out;

    CostDifference_kernel<<<800, 256, 0, stream>>>(left, right, out);
}